// Round 5
// baseline (240.067 us; speedup 1.0000x reference)
//
#include <hip/hip_runtime.h>
#include <hip/hip_bf16.h>

#define TT 16384
#define DM 256
#define NE 8
#define HF 512

typedef __bf16 bf16x8 __attribute__((ext_vector_type(8)));
typedef float f32x4 __attribute__((ext_vector_type(4)));

__device__ __forceinline__ unsigned f2bf(float f) {
  unsigned u = __float_as_uint(f);
  u += 0x7fffu + ((u >> 16) & 1u);  // RNE
  return u >> 16;
}

__device__ __forceinline__ void expert_range(const int* __restrict__ cnts, int e,
                                             int* s0, int* cnt) {
  int st = 0, c_e = 0, s_e = 0;
#pragma unroll
  for (int i = 0; i < NE; i++) {
    int c = cnts[i];
    if (i == e) { c_e = c; s_e = st; }
    st += (c + 63) & ~63;
  }
  *s0 = s_e; *cnt = c_e;
}

// ---- gate: thread=(token,expert), fp64 scores, top-2, list build, out=b2 init ----
__global__ __launch_bounds__(256) void gate_kernel(
    const float* __restrict__ x, const float* __restrict__ Wg,
    const float* __restrict__ bg, const float* __restrict__ b2,
    int* __restrict__ cnts, int* __restrict__ list, float* __restrict__ out) {
  __shared__ int hist[NE], base_s[NE], rank[NE];
  int tid = threadIdx.x;
  if (tid < NE) { hist[tid] = 0; rank[tid] = 0; }
  __syncthreads();

  int tl = tid >> 3, e = tid & 7, lane = tid & 63;
  int t = blockIdx.x * 32 + tl;
  const float* xr = x + (size_t)t * DM;
  double a0 = 0, a1 = 0, a2 = 0, a3 = 0;
  for (int d = 0; d < DM; d += 4) {
    float4 v = *reinterpret_cast<const float4*>(xr + d);
    a0 += (double)v.x * (double)Wg[(d + 0) * NE + e];
    a1 += (double)v.y * (double)Wg[(d + 1) * NE + e];
    a2 += (double)v.z * (double)Wg[(d + 2) * NE + e];
    a3 += (double)v.w * (double)Wg[(d + 3) * NE + e];
  }
  double s = ((a0 + a1) + (a2 + a3)) + (double)bg[e];

  double sc[8];
#pragma unroll
  for (int k = 0; k < 8; k++) sc[k] = __shfl(s, (lane & 56) | k);
  int e1 = 0;
#pragma unroll
  for (int k = 1; k < 8; k++) if (sc[k] > sc[e1]) e1 = k;  // ties -> lower index
  int e2 = -1;
#pragma unroll
  for (int k = 0; k < 8; k++) {
    if (k == e1) continue;
    if (e2 < 0 || sc[k] > sc[e2]) e2 = k;
  }

  if (e == 0) { atomicAdd(&hist[e1], 1); atomicAdd(&hist[e2], 1); }
  __syncthreads();
  if (tid < NE) base_s[tid] = atomicAdd(&cnts[tid], hist[tid]);
  __syncthreads();
  if (e == 0) {
    int r1 = atomicAdd(&rank[e1], 1);
    list[e1 * TT + base_s[e1] + r1] = t;
    int r2 = atomicAdd(&rank[e2], 1);
    list[e2 * TT + base_s[e2] + r2] = t;
  }

  const float* p1 = b2 + e1 * DM + e * 32;
  const float* p2 = b2 + e2 * DM + e * 32;
  float* orow = out + (size_t)t * DM + e * 32;
#pragma unroll
  for (int j = 0; j < 32; j += 4) {
    float4 u = *reinterpret_cast<const float4*>(p1 + j);
    float4 v = *reinterpret_cast<const float4*>(p2 + j);
    float4 o;
    o.x = u.x + v.x; o.y = u.y + v.y; o.z = u.z + v.z; o.w = u.w + v.w;
    *reinterpret_cast<float4*>(orow + j) = o;
  }
}

// ---- fused transpose+cast: W1 [D][H]->w1t[H][D], W2 [H][D]->w2t[D][H], bf16 ------
__global__ __launch_bounds__(256) void transpose_kernel(
    const float* __restrict__ W1, const float* __restrict__ W2,
    unsigned short* __restrict__ w1t, unsigned short* __restrict__ w2t) {
  __shared__ float tile[32][33];
  int bx = blockIdx.x;
  int which = bx >> 10;
  int rem = bx & 1023;
  int e = rem >> 7, t = rem & 127;
  const float* src;
  unsigned short* dst;
  int R, C, cx, ry;
  if (which == 0) {
    R = DM; C = HF;
    src = W1 + (size_t)e * R * C; dst = w1t + (size_t)e * R * C;
    cx = t & 15; ry = t >> 4;
  } else {
    R = HF; C = DM;
    src = W2 + (size_t)e * R * C; dst = w2t + (size_t)e * R * C;
    cx = t & 7; ry = t >> 3;
  }
  int c0 = cx * 32, r0 = ry * 32;
  int tx = threadIdx.x & 31, ty = threadIdx.x >> 5;
#pragma unroll
  for (int i = 0; i < 4; i++)
    tile[ty + i * 8][tx] = src[(size_t)(r0 + ty + i * 8) * C + c0 + tx];
  __syncthreads();
#pragma unroll
  for (int i = 0; i < 4; i++)
    dst[(size_t)(c0 + ty + i * 8) * R + r0 + tx] =
        (unsigned short)f2bf(tile[tx][ty + i * 8]);
}

// ---- G1: H[slot][h] = gelu(X @ W1^T + b1), per-expert compacted slots -----------
// m=token (A = Xf LDS frags), n=h (B = w1t rows, global), k=D. One barrier.
__global__ __launch_bounds__(512, 4) void g1_kernel(
    const float* __restrict__ x, const unsigned short* __restrict__ w1t,
    const float* __restrict__ b1, const int* __restrict__ cnts,
    const int* __restrict__ list, unsigned short* __restrict__ H) {
  __shared__ __align__(16) unsigned short Xf[64 * DM];  // 32 KB, A-frag order
  int e = blockIdx.x >> 8, tile = blockIdx.x & 255;
  int s0, cnt;
  expert_range(cnts, e, &s0, &cnt);
  int base = tile * 64;
  if (base >= cnt) return;

  int tid = threadIdx.x, w = tid >> 6, lane = tid & 63;
  int quad = lane >> 4, l16 = lane & 15;

  {  // stage Xf: wave w -> (mt = w&3, ks-half = w>>2); lane-linear writes
    int mtw = w & 3, kh = w >> 2;
    int tl = mtw * 16 + l16;
    int token = (base + tl < cnt) ? list[e * TT + base + tl] : -1;
    unsigned short* dst0 = Xf + ((mtw * 8 + kh * 4) * 64 + lane) * 8;
    if (token >= 0) {
      const float* xr = x + (size_t)token * DM + kh * 128 + quad * 8;
#pragma unroll
      for (int k = 0; k < 4; k++) {
        float4 v0 = *reinterpret_cast<const float4*>(xr + k * 32);
        float4 v1 = *reinterpret_cast<const float4*>(xr + k * 32 + 4);
        uint4 pk;
        pk.x = f2bf(v0.x) | (f2bf(v0.y) << 16);
        pk.y = f2bf(v0.z) | (f2bf(v0.w) << 16);
        pk.z = f2bf(v1.x) | (f2bf(v1.y) << 16);
        pk.w = f2bf(v1.z) | (f2bf(v1.w) << 16);
        *reinterpret_cast<uint4*>(dst0 + k * 512) = pk;
      }
    } else {
      uint4 z = {0, 0, 0, 0};
#pragma unroll
      for (int k = 0; k < 4; k++)
        *reinterpret_cast<uint4*>(dst0 + k * 512) = z;
    }
  }
  __syncthreads();  // the only barrier

  // wave w owns h-slice [w*64, w*64+64)
  const unsigned short* w1p =
      w1t + (size_t)e * HF * DM + (size_t)(w * 64 + l16) * DM + quad * 8;
  f32x4 pacc[4][4];
#pragma unroll
  for (int mt = 0; mt < 4; mt++)
#pragma unroll
    for (int nt = 0; nt < 4; nt++) pacc[mt][nt] = (f32x4){0.f, 0.f, 0.f, 0.f};

#pragma unroll
  for (int ks = 0; ks < 8; ks++) {
    bf16x8 bfr[4], afr[4];
#pragma unroll
    for (int nt = 0; nt < 4; nt++)
      bfr[nt] = *reinterpret_cast<const bf16x8*>(w1p + (size_t)(nt * 16) * DM + ks * 32);
#pragma unroll
    for (int mt = 0; mt < 4; mt++)
      afr[mt] = *reinterpret_cast<const bf16x8*>(Xf + ((mt * 8 + ks) * 64 + lane) * 8);
#pragma unroll
    for (int mt = 0; mt < 4; mt++)
#pragma unroll
      for (int nt = 0; nt < 4; nt++)
        pacc[mt][nt] = __builtin_amdgcn_mfma_f32_16x16x32_bf16(afr[mt], bfr[nt], pacc[mt][nt], 0, 0, 0);
  }

  float b1v[4];
#pragma unroll
  for (int nt = 0; nt < 4; nt++) b1v[nt] = b1[e * HF + w * 64 + nt * 16 + l16];

#pragma unroll
  for (int mt = 0; mt < 4; mt++) {
    size_t hrow = (size_t)(s0 + base + mt * 16 + quad * 4) * HF + w * 64 + l16;
#pragma unroll
    for (int r = 0; r < 4; r++) {
#pragma unroll
      for (int nt = 0; nt < 4; nt++) {
        float v = pacc[mt][nt][r] + b1v[nt];
        float g = 0.5f * v * (1.0f + erff(v * 0.70710678118654752f));
        H[hrow + (size_t)r * HF + nt * 16] = (unsigned short)f2bf(g);
      }
    }
  }
}

// ---- G2: out += H @ W2^T (per expert), coalesced 2-add/elt atomics ---------------
// m=token (A = H rows, global), n=d (B = w2t rows, global), k=HF. No LDS/barriers.
__global__ __launch_bounds__(256, 4) void g2_kernel(
    const unsigned short* __restrict__ H, const unsigned short* __restrict__ w2t,
    const int* __restrict__ cnts, const int* __restrict__ list,
    float* __restrict__ out) {
  int e = blockIdx.x >> 8, tile = blockIdx.x & 255;
  int s0, cnt;
  expert_range(cnts, e, &s0, &cnt);
  int base = tile * 64;
  if (base >= cnt) return;

  int tid = threadIdx.x, w = tid >> 6, lane = tid & 63;
  int quad = lane >> 4, l16 = lane & 15;

  const unsigned short* Hp = H + (size_t)(s0 + base + l16) * HF + quad * 8;
  const unsigned short* w2p =
      w2t + (size_t)e * DM * HF + (size_t)(w * 64 + l16) * HF + quad * 8;

  f32x4 oacc[4][4];
#pragma unroll
  for (int mt = 0; mt < 4; mt++)
#pragma unroll
    for (int nt = 0; nt < 4; nt++) oacc[mt][nt] = (f32x4){0.f, 0.f, 0.f, 0.f};

#pragma unroll
  for (int ks = 0; ks < 16; ks++) {
    bf16x8 ha[4], bfr[4];
#pragma unroll
    for (int mt = 0; mt < 4; mt++)
      ha[mt] = *reinterpret_cast<const bf16x8*>(Hp + (size_t)(mt * 16) * HF + ks * 32);
#pragma unroll
    for (int nt = 0; nt < 4; nt++)
      bfr[nt] = *reinterpret_cast<const bf16x8*>(w2p + (size_t)(nt * 16) * HF + ks * 32);
#pragma unroll
    for (int mt = 0; mt < 4; mt++)
#pragma unroll
      for (int nt = 0; nt < 4; nt++)
        oacc[mt][nt] = __builtin_amdgcn_mfma_f32_16x16x32_bf16(ha[mt], bfr[nt], oacc[mt][nt], 0, 0, 0);
  }

#pragma unroll
  for (int mt = 0; mt < 4; mt++) {
#pragma unroll
    for (int r = 0; r < 4; r++) {
      int row = base + mt * 16 + quad * 4 + r;
      if (row >= cnt) continue;
      int token = list[e * TT + row];
      float* orow = out + (size_t)token * DM + w * 64;
#pragma unroll
      for (int nt = 0; nt < 4; nt++)
        atomicAdd(orow + nt * 16 + l16, oacc[mt][nt][r]);
    }
  }
}

// ---- fallback fused FFN (R4) for small ws_size -----------------------------------
__global__ __launch_bounds__(256, 2) void ffn_kernel(
    const float* __restrict__ x, const unsigned short* __restrict__ w1t,
    const float* __restrict__ b1, const unsigned short* __restrict__ w2t,
    const int* __restrict__ cnts, const int* __restrict__ list,
    float* __restrict__ out) {
  __shared__ __align__(16) unsigned short Xf[64 * DM];
  __shared__ __align__(16) unsigned short Hs[64 * 256];
  __shared__ int tok_s[64];

  int e = blockIdx.x >> 8;
  int tile = blockIdx.x & 255;
  int cnt = cnts[e];
  int base = tile * 64;
  if (base >= cnt) return;

  int tid = threadIdx.x;
  int w = tid >> 6, lane = tid & 63;
  int quad = lane >> 4, l16 = lane & 15;

  {
    int tl = w * 16 + l16;
    int token = (base + tl < cnt) ? list[e * TT + base + tl] : -1;
    if (quad == 0) tok_s[tl] = token;
    unsigned short* dst0 = Xf + ((w * 8) * 64 + lane) * 8;
    if (token >= 0) {
      const float* xr = x + (size_t)token * DM + quad * 8;
#pragma unroll
      for (int ks = 0; ks < 8; ks++) {
        float4 v0 = *reinterpret_cast<const float4*>(xr + ks * 32);
        float4 v1 = *reinterpret_cast<const float4*>(xr + ks * 32 + 4);
        uint4 pk;
        pk.x = f2bf(v0.x) | (f2bf(v0.y) << 16);
        pk.y = f2bf(v0.z) | (f2bf(v0.w) << 16);
        pk.z = f2bf(v1.x) | (f2bf(v1.y) << 16);
        pk.w = f2bf(v1.z) | (f2bf(v1.w) << 16);
        *reinterpret_cast<uint4*>(dst0 + ks * 512) = pk;
      }
    } else {
      uint4 z = {0, 0, 0, 0};
#pragma unroll
      for (int ks = 0; ks < 8; ks++)
        *reinterpret_cast<uint4*>(dst0 + ks * 512) = z;
    }
  }
  __syncthreads();

  const unsigned short* w1e = w1t + (size_t)e * HF * DM;
  const unsigned short* w2e = w2t + (size_t)e * DM * HF;

  f32x4 oacc[4][4];
#pragma unroll
  for (int mt = 0; mt < 4; mt++)
#pragma unroll
    for (int nt = 0; nt < 4; nt++) oacc[mt][nt] = (f32x4){0.f, 0.f, 0.f, 0.f};

#pragma unroll
  for (int p = 0; p < 2; p++) {
    f32x4 pacc[4][4];
#pragma unroll
    for (int mt = 0; mt < 4; mt++)
#pragma unroll
      for (int nt = 0; nt < 4; nt++) pacc[mt][nt] = (f32x4){0.f, 0.f, 0.f, 0.f};

    const unsigned short* w1p = w1e + (size_t)(p * 256 + w * 64) * DM;
#pragma unroll
    for (int ks = 0; ks < 8; ks++) {
      bf16x8 xb[4];
#pragma unroll
      for (int nt = 0; nt < 4; nt++)
        xb[nt] = *reinterpret_cast<const bf16x8*>(Xf + ((nt * 8 + ks) * 64 + lane) * 8);
#pragma unroll
      for (int mt = 0; mt < 4; mt++) {
        bf16x8 af = *reinterpret_cast<const bf16x8*>(
            w1p + (size_t)(mt * 16 + l16) * DM + ks * 32 + quad * 8);
#pragma unroll
        for (int nt = 0; nt < 4; nt++)
          pacc[mt][nt] = __builtin_amdgcn_mfma_f32_16x16x32_bf16(af, xb[nt], pacc[mt][nt], 0, 0, 0);
      }
    }

    float4 bb[4];
#pragma unroll
    for (int mt = 0; mt < 4; mt++)
      bb[mt] = *reinterpret_cast<const float4*>(
          b1 + e * HF + p * 256 + w * 64 + mt * 16 + quad * 4);

    if (p == 1) __syncthreads();

#pragma unroll
    for (int mt = 0; mt < 4; mt++) {
      int ks2 = w * 2 + (mt >> 1);
      int rquad = (mt & 1) * 2 + (quad >> 1);
      const float* bbp = reinterpret_cast<const float*>(&bb[mt]);
#pragma unroll
      for (int nt = 0; nt < 4; nt++) {
        float g[4];
#pragma unroll
        for (int r = 0; r < 4; r++) {
          float v = pacc[mt][nt][r] + bbp[r];
          g[r] = 0.5f * v * (1.0f + erff(v * 0.70710678118654752f));
        }
        unsigned short* hp =
            Hs + ((ks2 * 4 + nt) * 64 + rquad * 16 + l16) * 8 + (quad & 1) * 4;
        *reinterpret_cast<unsigned*>(hp) = f2bf(g[0]) | (f2bf(g[1]) << 16);
        *reinterpret_cast<unsigned*>(hp + 2) = f2bf(g[2]) | (f2bf(g[3]) << 16);
      }
    }
    __syncthreads();

#pragma unroll
    for (int ks = 0; ks < 8; ks++) {
      bf16x8 ha[4];
#pragma unroll
      for (int mt = 0; mt < 4; mt++)
        ha[mt] = *reinterpret_cast<const bf16x8*>(Hs + ((ks * 4 + mt) * 64 + lane) * 8);
#pragma unroll
      for (int nt = 0; nt < 4; nt++) {
        bf16x8 bf = *reinterpret_cast<const bf16x8*>(
            w2e + (size_t)(w * 64 + nt * 16 + l16) * HF + p * 256 + ks * 32 + quad * 8);
#pragma unroll
        for (int mt = 0; mt < 4; mt++)
          oacc[mt][nt] = __builtin_amdgcn_mfma_f32_16x16x32_bf16(ha[mt], bf, oacc[mt][nt], 0, 0, 0);
      }
    }
  }

#pragma unroll
  for (int mt = 0; mt < 4; mt++) {
#pragma unroll
    for (int r = 0; r < 4; r++) {
      int token = tok_s[mt * 16 + quad * 4 + r];
      if (token < 0) continue;
      float* orow = out + (size_t)token * DM + w * 64;
#pragma unroll
      for (int nt = 0; nt < 4; nt++)
        atomicAdd(orow + nt * 16 + l16, oacc[mt][nt][r]);
    }
  }
}

extern "C" void kernel_launch(void* const* d_in, const int* in_sizes, int n_in,
                              void* d_out, int out_size, void* d_ws, size_t ws_size,
                              hipStream_t stream) {
  (void)in_sizes; (void)n_in; (void)out_size;
  const float* x  = (const float*)d_in[0];
  const float* Wg = (const float*)d_in[1];
  const float* bg = (const float*)d_in[2];
  const float* W1 = (const float*)d_in[3];
  const float* b1 = (const float*)d_in[4];
  const float* W2 = (const float*)d_in[5];
  const float* b2 = (const float*)d_in[6];
  float* out = (float*)d_out;

  char* ws = (char*)d_ws;
  int* cnts = (int*)ws;                                                  // 256 B
  int* list = (int*)(ws + 256);                                          // 512 KB
  unsigned short* w1t = (unsigned short*)(ws + 256 + 524288);            // 2 MB
  unsigned short* w2t = (unsigned short*)(ws + 256 + 524288 + 2097152);  // 2 MB
  size_t off_H = 256 + 524288 + 2097152 + 2097152;
  unsigned short* Hbuf = (unsigned short*)(ws + off_H);
  size_t H_bytes = (size_t)(32768 + 64 * NE) * HF * 2;  // ~34.1 MB
  bool split = (ws_size >= off_H + H_bytes);

  hipMemsetAsync(cnts, 0, 256, stream);

  hipLaunchKernelGGL(gate_kernel, dim3(TT / 32), dim3(256), 0, stream,
                     x, Wg, bg, b2, cnts, list, out);
  hipLaunchKernelGGL(transpose_kernel, dim3(2 * NE * 128), dim3(256), 0, stream,
                     W1, W2, w1t, w2t);
  if (split) {
    hipLaunchKernelGGL(g1_kernel, dim3(NE * 256), dim3(512), 0, stream,
                       x, w1t, b1, cnts, list, Hbuf);
    hipLaunchKernelGGL(g2_kernel, dim3(NE * 256), dim3(256), 0, stream,
                       Hbuf, w2t, cnts, list, out);
  } else {
    hipLaunchKernelGGL(ffn_kernel, dim3(NE * 256), dim3(256), 0, stream,
                       x, w1t, b1, w2t, cnts, list, out);
  }
}